// Round 4
// baseline (12045.352 us; speedup 1.0000x reference)
//
#include <hip/hip_runtime.h>

// Problem constants
#define NB 256   // batch
#define TT 256   // time steps
#define II 512   // input dim
#define HH 512   // hidden dim
#define GG 1536  // 3*H gates

typedef unsigned short ushort_t;
typedef unsigned int uint_t;
typedef __attribute__((ext_vector_type(8))) short short8;   // 8 x bf16 (4 VGPRs)
typedef __attribute__((ext_vector_type(4))) float f32x4;    // MFMA accumulator

__device__ __forceinline__ ushort_t f2bf(float f) {
  union { float f; unsigned int u; } x; x.f = f;
  unsigned int r = x.u + 0x7FFFu + ((x.u >> 16) & 1u);  // RNE
  return (ushort_t)(r >> 16);
}
__device__ __forceinline__ float bf2f(ushort_t b) {
  union { unsigned int u; float f; } x; x.u = ((unsigned int)b) << 16;
  return x.f;
}
__device__ __forceinline__ float sigmoidf_(float x) {
  return __fdividef(1.0f, 1.0f + __expf(-x));
}
__device__ __forceinline__ float tanhf_(float x) {
  float t = __expf(2.0f * x);
  return 1.0f - __fdividef(2.0f, t + 1.0f);
}
__device__ __forceinline__ short8 pack8(float4 a, float4 b) {
  short8 r;
  r[0] = (short)f2bf(a.x); r[1] = (short)f2bf(a.y);
  r[2] = (short)f2bf(a.z); r[3] = (short)f2bf(a.w);
  r[4] = (short)f2bf(b.x); r[5] = (short)f2bf(b.y);
  r[6] = (short)f2bf(b.z); r[7] = (short)f2bf(b.w);
  return r;
}

// ---------------------------------------------------------------------------
// is_init canonicalization -> uint8 mask (handles u8/i32/f32/i64 storage).
__global__ void mask_detect_kernel(const unsigned char* __restrict__ src,
                                   unsigned char* __restrict__ mask8) {
  __shared__ int fByte, fOdd;
  const int tid = threadIdx.x;
  if (tid == 0) { fByte = 0; fOdd = 0; }
  __syncthreads();
  const uint_t* w = (const uint_t*)src;
  int ab = 0, ao = 0;
  for (int i = tid; i < NB * TT; i += blockDim.x) {
    if ((i & 3) == 1 && src[i]) ab = 1;
    if (i < 16384 && (i & 1) == 1 && w[i]) ao = 1;
  }
  if (ab) fByte = 1;
  if (ao) fOdd = 1;
  __syncthreads();
  const int isByte = fByte, isW32 = fOdd;
  for (int i = tid; i < NB * TT; i += blockDim.x) {
    unsigned char m;
    if (isByte)      m = src[i] ? 1 : 0;
    else if (isW32)  m = w[i] ? 1 : 0;
    else             m = w[2 * i] ? 1 : 0;
    mask8[i] = m;
  }
}

// ---------------------------------------------------------------------------
__global__ void cvt_f2bf(const float* __restrict__ src, ushort_t* __restrict__ dst,
                         int n4) {
  int stride = gridDim.x * blockDim.x;
  for (int i = blockIdx.x * blockDim.x + threadIdx.x; i < n4; i += stride) {
    const float4 v = reinterpret_cast<const float4*>(src)[i];
    ushort4 o;
    o.x = f2bf(v.x); o.y = f2bf(v.y); o.z = f2bf(v.z); o.w = f2bf(v.w);
    reinterpret_cast<ushort4*>(dst)[i] = o;
  }
}

// ---------------------------------------------------------------------------
// Pack W_hh [1536][512] f32 into MFMA-B-fragment order (bf16):
// Wpk[((tile*16+kk)*64 + lane)*8 + e] = W[tile*16 + (lane&15)][kk*32 + (lane>>4)*8 + e]
__global__ void pack_whh(const float* __restrict__ W, ushort_t* __restrict__ out) {
  int idx = blockIdx.x * blockDim.x + threadIdx.x;  // 96*16*64 = 98304
  if (idx >= 96 * 16 * 64) return;
  int l = idx & 63;
  int tk = idx >> 6;
  int tile = tk >> 4, kk = tk & 15;
  int row = tile * 16 + (l & 15);
  int k = kk * 32 + (l >> 4) * 8;
  const float* s = W + (size_t)row * HH + k;
  short8 v;
#pragma unroll
  for (int e = 0; e < 8; ++e) v[e] = (short)f2bf(s[e]);
  *reinterpret_cast<short8*>(out + (size_t)idx * 8) = v;
}

// ---------------------------------------------------------------------------
// GEMM: C[m][c] = sum_k A[m][k]*B[c][k] + bias[c].  (unchanged from R3)
template <int AF32, int CF32>
__global__ __launch_bounds__(256) void gemm_bt(
    const void* __restrict__ Av, const ushort_t* __restrict__ B,
    const float* __restrict__ bias, void* __restrict__ Cv, int NC) {
  __shared__ ushort_t As[128 * 32];
  __shared__ ushort_t Bs[128 * 32];
  const int tid = threadIdx.x;
  const int lane = tid & 63;
  const int w = tid >> 6;
  const int wr = w >> 1, wc = w & 1;
  const int c15 = lane & 15, l4 = lane >> 4;
  const int mbase = blockIdx.x * 128;
  const int nbase = blockIdx.y * 128;

  const int rs = tid >> 2;
  const int kb = (tid & 3) * 8;

  f32x4 acc[4][4] = {};

  const float4* Bg = reinterpret_cast<const float4*>(B);
  auto bIdx = [&](int c, int kt) {
    return ((size_t)(nbase + rs + 64 * c) * 512 + kt * 32 + kb) >> 3;
  };
  float4 rb0 = Bg[bIdx(0, 0)], rb1 = Bg[bIdx(1, 0)];

  const float4* Agf = reinterpret_cast<const float4*>(Av);
  auto aEl = [&](int c, int kt) {
    return (size_t)(mbase + rs + 64 * c) * 512 + kt * 32 + kb;
  };
  float4 a0a, a0b, a1a, a1b;
  float4 h0, h1;
  if constexpr (AF32) {
    a0a = Agf[aEl(0, 0) >> 2]; a0b = Agf[(aEl(0, 0) >> 2) + 1];
    a1a = Agf[aEl(1, 0) >> 2]; a1b = Agf[(aEl(1, 0) >> 2) + 1];
  } else {
    h0 = Agf[aEl(0, 0) >> 3];
    h1 = Agf[aEl(1, 0) >> 3];
  }

  for (int kt = 0; kt < 16; ++kt) {
    __syncthreads();
    if constexpr (AF32) {
      *reinterpret_cast<short8*>(&As[(size_t)tid * 8]) = pack8(a0a, a0b);
      *reinterpret_cast<short8*>(&As[(size_t)(tid + 256) * 8]) = pack8(a1a, a1b);
    } else {
      reinterpret_cast<float4*>(As)[tid] = h0;
      reinterpret_cast<float4*>(As)[tid + 256] = h1;
    }
    reinterpret_cast<float4*>(Bs)[tid] = rb0;
    reinterpret_cast<float4*>(Bs)[tid + 256] = rb1;
    if (kt < 15) {
      if constexpr (AF32) {
        a0a = Agf[aEl(0, kt + 1) >> 2]; a0b = Agf[(aEl(0, kt + 1) >> 2) + 1];
        a1a = Agf[aEl(1, kt + 1) >> 2]; a1b = Agf[(aEl(1, kt + 1) >> 2) + 1];
      } else {
        h0 = Agf[aEl(0, kt + 1) >> 3];
        h1 = Agf[aEl(1, kt + 1) >> 3];
      }
      rb0 = Bg[bIdx(0, kt + 1)]; rb1 = Bg[bIdx(1, kt + 1)];
    }
    __syncthreads();
    short8 af[4], bq[4];
#pragma unroll
    for (int m = 0; m < 4; ++m)
      af[m] = *reinterpret_cast<const short8*>(&As[(wr * 64 + m * 16 + c15) * 32 + l4 * 8]);
#pragma unroll
    for (int n = 0; n < 4; ++n)
      bq[n] = *reinterpret_cast<const short8*>(&Bs[(wc * 64 + n * 16 + c15) * 32 + l4 * 8]);
#pragma unroll
    for (int m = 0; m < 4; ++m)
#pragma unroll
      for (int n = 0; n < 4; ++n)
        acc[m][n] = __builtin_amdgcn_mfma_f32_16x16x32_bf16(af[m], bq[n], acc[m][n], 0, 0, 0);
  }

#pragma unroll
  for (int n = 0; n < 4; ++n) {
    const int col = nbase + wc * 64 + n * 16 + c15;
    const float bv = bias[col];
#pragma unroll
    for (int m = 0; m < 4; ++m) {
      const int row = mbase + wr * 64 + m * 16 + l4 * 4;
#pragma unroll
      for (int q = 0; q < 4; ++q) {
        const float v = acc[m][n][q] + bv;
        if constexpr (CF32)
          reinterpret_cast<float*>(Cv)[(size_t)(row + q) * NC + col] = v;
        else
          reinterpret_cast<ushort_t*>(Cv)[(size_t)(row + q) * NC + col] = f2bf(v);
      }
    }
  }
}

// ---------------------------------------------------------------------------
// GRU recurrence v2. 16 blocks x 1024 threads (16 waves, 4/SIMD).
// Block owns 16 samples; wave w owns hidden cols [w*32,(w+1)*32) x 3 gates
// (6 MFMA tiles). h lives in REGISTERS (thread owns its 8 (s,J) outputs).
// Per step: [bar] MFMA (W dbuf'd in regs; xi[t] reg-staged->LDS; mask
// prefetch) [bar] gates from regs+LDS, write h regs + hB + hs. 2 bars/step.
// LDS: hB 16KB (XOR-swizzled) + xiL 48KB = 64KB exactly.
__global__ __launch_bounds__(1024) void gru_rec(
    const ushort_t* __restrict__ xi, const ushort_t* __restrict__ Wpk,
    const float* __restrict__ hx, const float* __restrict__ bhh,
    const unsigned char* __restrict__ mask8,
    ushort_t* __restrict__ hs, float* __restrict__ hT) {
  __shared__ ushort_t hB[16 * 512];    // bf16 h, XOR-swizzled rows
  __shared__ ushort_t xiL[16 * 1536];  // xi[t] staging
  const int tid = threadIdx.x;
  const int lane = tid & 63;
  const int w = tid >> 6;              // wave 0..15 -> j-slice w*32
  const int c15 = lane & 15, l4 = lane >> 4;
  const int n0 = blockIdx.x * 16;

  // hB byte-offset with XOR swizzle: row-stride 1024B is a 16-way bank
  // conflict for the b128 A-read; XOR bits 4-6 with (row&7) fixes it [G4].
  auto hbOff = [](int row, int colByte) {
    return row * 1024 + (colByte ^ ((row & 7) << 4));
  };

  // per-thread ownership: samples s(q)=l4*4+q, cols J(t2)=w*32+t2*16+c15
  int J[2];  float br[2], bz[2], bn[2];
#pragma unroll
  for (int t2 = 0; t2 < 2; ++t2) {
    J[t2] = w * 32 + t2 * 16 + c15;
    br[t2] = bhh[J[t2]];
    bz[t2] = bhh[512 + J[t2]];
    bn[t2] = bhh[1024 + J[t2]];
  }

  // W_hh fragment base offsets (ushort units): tile(i) = (i>>1)*32 + w*2 + (i&1)
  int Bbase[6];
#pragma unroll
  for (int i = 0; i < 6; ++i) {
    const int tile = (i >> 1) * 32 + w * 2 + (i & 1);
    Bbase[i] = tile * 8192 + lane * 8;   // ((tile*16+kk)*64+lane)*8, kk=0
  }

  // xi staging geometry: 3072 16B-chunks = [16 rows][192 chunks]; 3/thread.
  int xgOff[3], xlOff[3];
#pragma unroll
  for (int k = 0; k < 3; ++k) {
    const int c = tid + k * 1024;
    const int sK = c / 192, ch = c % 192;
    xgOff[k] = (n0 + sK) * TT * GG + ch * 8;  // + t*GG each step
    xlOff[k] = sK * 1536 + ch * 8;
  }

  // init h regs + hB (mask[0] applied)
  float h[2][4];
#pragma unroll
  for (int q = 0; q < 4; ++q) {
    const int s = l4 * 4 + q;
    const bool mk0 = mask8[(size_t)(n0 + s) * TT] != 0;
#pragma unroll
    for (int t2 = 0; t2 < 2; ++t2) {
      float v = mk0 ? 0.0f : hx[(size_t)(n0 + s) * TT * HH + J[t2]];
      h[t2][q] = v;
      *(ushort_t*)((char*)hB + hbOff(s, J[t2] * 2)) = f2bf(v);
    }
  }
  __syncthreads();

  for (int t = 0; t < TT; ++t) {
    // ---- phase B: issue xi loads early (T14), MFMA with 1-deep W prefetch
    short8 xv0 = *(const short8*)(xi + (size_t)xgOff[0] + (size_t)t * GG);
    short8 xv1 = *(const short8*)(xi + (size_t)xgOff[1] + (size_t)t * GG);
    short8 xv2 = *(const short8*)(xi + (size_t)xgOff[2] + (size_t)t * GG);
    // prefetch next-step mask bytes (L1-hot after first steps)
    const int tn = (t + 1 < TT) ? (t + 1) : t;
    unsigned char mkv[4];
#pragma unroll
    for (int q = 0; q < 4; ++q)
      mkv[q] = mask8[(size_t)(n0 + l4 * 4 + q) * TT + tn];

    f32x4 acc[6];
#pragma unroll
    for (int i = 0; i < 6; ++i) acc[i] = (f32x4){0.f, 0.f, 0.f, 0.f};

    short8 a0, a1, b0[6], b1[6];
    a0 = *(const short8*)((char*)hB + hbOff(c15, l4 * 16));
#pragma unroll
    for (int i = 0; i < 6; ++i) b0[i] = *(const short8*)(Wpk + Bbase[i]);

#pragma unroll
    for (int kk = 0; kk < 16; ++kk) {
      if (kk < 15) {
        if (kk & 1) {
          a0 = *(const short8*)((char*)hB + hbOff(c15, (kk + 1) * 64 + l4 * 16));
#pragma unroll
          for (int i = 0; i < 6; ++i)
            b0[i] = *(const short8*)(Wpk + Bbase[i] + (kk + 1) * 512);
        } else {
          a1 = *(const short8*)((char*)hB + hbOff(c15, (kk + 1) * 64 + l4 * 16));
#pragma unroll
          for (int i = 0; i < 6; ++i)
            b1[i] = *(const short8*)(Wpk + Bbase[i] + (kk + 1) * 512);
        }
      }
      if (kk & 1) {
#pragma unroll
        for (int i = 0; i < 6; ++i)
          acc[i] = __builtin_amdgcn_mfma_f32_16x16x32_bf16(a1, b1[i], acc[i], 0, 0, 0);
      } else {
#pragma unroll
        for (int i = 0; i < 6; ++i)
          acc[i] = __builtin_amdgcn_mfma_f32_16x16x32_bf16(a0, b0[i], acc[i], 0, 0, 0);
      }
    }

    // write-late xi staging (HBM latency hidden under the MFMA loop)
    *(short8*)&xiL[xlOff[0]] = xv0;
    *(short8*)&xiL[xlOff[1]] = xv1;
    *(short8*)&xiL[xlOff[2]] = xv2;
    __syncthreads();

    // ---- phase C: gates + h update (h regs), write hB for next step + hs
    const bool domask = (t + 1 < TT);
#pragma unroll
    for (int t2 = 0; t2 < 2; ++t2) {
      const int Jt = J[t2];
#pragma unroll
      for (int q = 0; q < 4; ++q) {
        const int s = l4 * 4 + q;
        const float xr = bf2f(xiL[s * 1536 + Jt]);
        const float xz = bf2f(xiL[s * 1536 + 512 + Jt]);
        const float xn = bf2f(xiL[s * 1536 + 1024 + Jt]);
        const float rr = sigmoidf_(xr + acc[t2][q] + br[t2]);
        const float zz = sigmoidf_(xz + acc[2 + t2][q] + bz[t2]);
        const float nn = tanhf_(xn + rr * (acc[4 + t2][q] + bn[t2]));
        const float hnew = (1.0f - zz) * nn + zz * h[t2][q];
        hs[((size_t)(n0 + s) * TT + t) * HH + Jt] = f2bf(hnew);
        const float hnext = (domask && mkv[q]) ? 0.0f : hnew;
        h[t2][q] = hnext;
        *(ushort_t*)((char*)hB + hbOff(s, Jt * 2)) = f2bf(hnext);
      }
    }
    __syncthreads();
  }

  // epilogue: hT (f32) for hx_out broadcast
#pragma unroll
  for (int t2 = 0; t2 < 2; ++t2)
#pragma unroll
    for (int q = 0; q < 4; ++q)
      hT[(size_t)(n0 + l4 * 4 + q) * HH + J[t2]] = h[t2][q];
}

// ---------------------------------------------------------------------------
// hx_out[n,t,:] = hT[n,:]  (f32, overwrites the hs scratch region after gemm3)
__global__ void bcast_hT(const float* __restrict__ hT, float* __restrict__ dst) {
  const float4* s = (const float4*)hT;
  float4* d = (float4*)dst;
  const int total = NB * TT * HH / 4;
  const int stride = gridDim.x * blockDim.x;
  for (int c = blockIdx.x * blockDim.x + threadIdx.x; c < total; c += stride) {
    int n = c >> 15;
    int j4 = c & 127;
    d[c] = s[(n << 7) | j4];
  }
}

// ---------------------------------------------------------------------------
extern "C" void kernel_launch(void* const* d_in, const int* in_sizes, int n_in,
                              void* d_out, int out_size, void* d_ws, size_t ws_size,
                              hipStream_t stream) {
  const float* x    = (const float*)d_in[0];
  const float* hx   = (const float*)d_in[1];
  const float* Wih  = (const float*)d_in[2];
  const float* Whh  = (const float*)d_in[3];
  const float* bih  = (const float*)d_in[4];
  const float* bhh  = (const float*)d_in[5];
  const float* Wout = (const float*)d_in[6];
  const float* bout = (const float*)d_in[7];
  const unsigned char* isinit = (const unsigned char*)d_in[8];

  char* ws = (char*)d_ws;
  ushort_t* xi    = (ushort_t*)(ws);
  ushort_t* wihb  = (ushort_t*)(ws + 201326592);
  ushort_t* whhp  = (ushort_t*)(ws + 202899456);
  ushort_t* woutb = (ushort_t*)(ws + 204472320);
  unsigned char* mask8 = (unsigned char*)(ws + 204996608);
  float*    hTbuf = (float*)(ws + 205062144);

  float* out1 = (float*)d_out;                       // output [N,T,H] f32
  float* out2 = out1 + (size_t)NB * TT * HH;         // hx_out [N,T,H] f32
  ushort_t* hsb = (ushort_t*)out2;  // hs bf16 scratch until bcast overwrites

  mask_detect_kernel<<<1, 1024, 0, stream>>>(isinit, mask8);
  cvt_f2bf<<<768, 256, 0, stream>>>(Wih, wihb, GG * II / 4);
  cvt_f2bf<<<256, 256, 0, stream>>>(Wout, woutb, HH * HH / 4);
  pack_whh<<<384, 256, 0, stream>>>(Whh, whhp);

  dim3 g1(512, 12);  // M/128 x 3H/128
  gemm_bt<1, 0><<<g1, 256, 0, stream>>>((const void*)x, wihb, bih, (void*)xi, GG);

  gru_rec<<<16, 1024, 0, stream>>>(xi, whhp, hx, bhh, mask8, hsb, hTbuf);

  dim3 g3(512, 4);   // M/128 x H/128
  gemm_bt<0, 1><<<g3, 256, 0, stream>>>((const void*)hsb, woutb, bout, (void*)out1, HH);

  bcast_hT<<<2048, 256, 0, stream>>>(hTbuf, out2);
}